// Round 7
// baseline (278.625 us; speedup 1.0000x reference)
//
#include <hip/hip_runtime.h>

// Problem constants
#define CV   34          // C*V channels
#define TTOT 2048        // T
#define NB   512         // batches
#define XB   69632       // x per-batch stride (2*2048*17)
#define XC   34816       // x per-co stride (2048*17)

// Workspace layout (floats): region B only
// per batch: 1024 ushort (hi/lo bf16 planes, 16x32) = 512 f,
// then cy[16], wy32[16], wy33[16] f32 -> 560 f, padded to 576
#define RB_STRIDE 576

typedef __attribute__((ext_vector_type(8))) short v8s;   // 8 x bf16 (MFMA A/B frag)
typedef __attribute__((ext_vector_type(4))) float v4f;   // 4 x f32 (MFMA C/D frag)

__device__ __forceinline__ unsigned short f2bf(float f) {
    unsigned int u = __float_as_uint(f);
    u = u + 0x7FFFu + ((u >> 16) & 1u);   // round-to-nearest-even
    return (unsigned short)(u >> 16);
}
__device__ __forceinline__ float bf2f(unsigned short s) {
    return __uint_as_float(((unsigned int)s) << 16);
}

__device__ __forceinline__ unsigned int cvtpk_bf16(float a, float b) {
    unsigned int r;   // r.lo16 = bf16(a), r.hi16 = bf16(b), RNE
    asm("v_cvt_pk_bf16_f32 %0, %1, %2" : "=v"(r) : "v"(a), "v"(b));
    return r;
}

// split 8 f32 -> packed hi/lo bf16 MFMA fragments (RNE; residual exact in f32)
__device__ __forceinline__ void split8(const float (&f)[8], v8s* hi, v8s* lo) {
    union { unsigned int u[4]; v8s s; } H, L;
#pragma unroll
    for (int p = 0; p < 4; ++p) {
        float a = f[2 * p], b = f[2 * p + 1];
        unsigned int h = cvtpk_bf16(a, b);
        float ra = a - __uint_as_float(h << 16);
        float rb = b - __uint_as_float(h & 0xFFFF0000u);
        L.u[p] = cvtpk_bf16(ra, rb);
        H.u[p] = h;
    }
    *hi = H.s;
    *lo = L.s;
}

// async-stage one 128-t chunk (2 co x 2176 floats, verbatim global order) to LDS.
// 17 x global_load_lds(16B); sub-wave w (0..3) issues instrs {w, w+4, ...}.
__device__ __forceinline__ void stage_chunk(const float* __restrict__ xb, int t0,
                                            float* rawbuf, int w, int lane) {
#pragma unroll
    for (int i = 0; i < 5; ++i) {
        int idx = i * 4 + w;
        if (idx < 17) {
            int fl = idx * 256 + lane * 4;
            int co = (fl >= 2176) ? 1 : 0;
            const float* g = xb + t0 * 17 + fl + co * 32640;   // 32640 = XC - 2176
            __builtin_amdgcn_global_load_lds(
                (const __attribute__((address_space(1))) void*)g,
                (__attribute__((address_space(3))) void*)(rawbuf + idx * 256),
                16, 0, 0);
        }
    }
}

// ---------------------------------------------------------------------------
// K_FUSED: per-batch Gram + affine chain, 512 threads (8 waves) per block.
// Gram: wave-group g = wave>>2 handles chunks {g, g+2, ...} (two chunks in
// flight), 4 k-slice waves per group, own double-buffer each -> 8 iterations.
// 8 register partials reduced in LDS. Chain: augmented-matrix MFMA chain;
// each mm's 9 tiles split across 8 waves (stage1: 27 tasks over 8 waves).
// LDS: 17408 f32 (69,632 B): staging 4x4352 aliases the 8 chain regions.
// ---------------------------------------------------------------------------
#define RST 44
#define RSZ (36 * RST)        // 1584 f32 per region
#define R_G0 0
#define R_At (1 * RSZ)
#define R_Aq (2 * RSZ)
#define R_Ak (3 * RSZ)
#define R_Av (4 * RSZ)        // AvT
#define R_S1 (5 * RSZ)
#define R_Sc (6 * RSZ)
#define R_Wx (7 * RSZ)
#define SMF  (8 * RSZ)        // 12672 f32 chain area
#define STF  17408            // total LDS floats (4 staging bufs x 4352)

__device__ __forceinline__ void ldfrag8(const float* p, v8s* hi, v8s* lo) {
    float f[8];
    *(float4*)&f[0] = *(const float4*)p;
    *(float4*)&f[4] = *(const float4*)(p + 4);
    split8(f, hi, lo);
}

// e = 32..35 frag: only quad 0 carries data (k elements 0..3), rest zero
__device__ __forceinline__ void ldfrag4(const float* p, int quad, v8s* hi, v8s* lo) {
    union { unsigned int u[4]; v8s s; } H, L;
#pragma unroll
    for (int i = 0; i < 4; ++i) { H.u[i] = 0; L.u[i] = 0; }
    if (quad == 0) {
        float4 f = *(const float4*)p;
        unsigned int h0 = cvtpk_bf16(f.x, f.y);
        unsigned int h1 = cvtpk_bf16(f.z, f.w);
        float r0 = f.x - __uint_as_float(h0 << 16);
        float r1 = f.y - __uint_as_float(h0 & 0xFFFF0000u);
        float r2 = f.z - __uint_as_float(h1 << 16);
        float r3 = f.w - __uint_as_float(h1 & 0xFFFF0000u);
        H.u[0] = h0; H.u[1] = h1;
        L.u[0] = cvtpk_bf16(r0, r1);
        L.u[1] = cvtpk_bf16(r2, r3);
    }
    *hi = H.s;
    *lo = L.s;
}

// One 16x16 tile of D[i][j] = sum_{e<36} L[i][e]*R[j][e] (stride RST; clamp
// rows 34/35 land in discarded outputs). transD=1 writes D[j][i].
__device__ __forceinline__ void tile_mm(float* __restrict__ SMD, int Lo, int Ro,
                                        int Do, int tm, int tn, int lane,
                                        bool transD) {
    const int lc = lane & 15, quad = lane >> 4;
    int ra = tm * 16 + lc; ra = ra < 36 ? ra : 35;
    const float* pa = SMD + Lo + ra * RST;
    v8s Ah0, Al0, Ah1, Al1;
    ldfrag8(pa + quad * 8, &Ah0, &Al0);
    ldfrag4(pa + 32, quad, &Ah1, &Al1);
    int rb = tn * 16 + lc; rb = rb < 36 ? rb : 35;
    const float* pb = SMD + Ro + rb * RST;
    v8s Bh0, Bl0, Bh1, Bl1;
    ldfrag8(pb + quad * 8, &Bh0, &Bl0);
    ldfrag4(pb + 32, quad, &Bh1, &Bl1);
    v4f acc = {0.f, 0.f, 0.f, 0.f};
    acc = __builtin_amdgcn_mfma_f32_16x16x32_bf16(Ah0, Bh0, acc, 0, 0, 0);
    acc = __builtin_amdgcn_mfma_f32_16x16x32_bf16(Ah0, Bl0, acc, 0, 0, 0);
    acc = __builtin_amdgcn_mfma_f32_16x16x32_bf16(Al0, Bh0, acc, 0, 0, 0);
    acc = __builtin_amdgcn_mfma_f32_16x16x32_bf16(Ah1, Bh1, acc, 0, 0, 0);
    acc = __builtin_amdgcn_mfma_f32_16x16x32_bf16(Ah1, Bl1, acc, 0, 0, 0);
    acc = __builtin_amdgcn_mfma_f32_16x16x32_bf16(Al1, Bh1, acc, 0, 0, 0);
    if (!transD) {
        int gcol = tn * 16 + lc;
        if (gcol < 36) {
#pragma unroll
            for (int i = 0; i < 4; ++i) {
                int grow = tm * 16 + quad * 4 + i;
                if (grow < 36) SMD[Do + grow * RST + gcol] = acc[i];
            }
        }
    } else {
        int trow = tn * 16 + lc;
        int tcol = tm * 16 + quad * 4;
        if (trow < 36 && tcol < 36)
            *(v4f*)&SMD[Do + trow * RST + tcol] = acc;
    }
}

__global__ __launch_bounds__(512) void k_fused(
    const float* __restrict__ x,
    const float* __restrict__ wq, const float* __restrict__ bq,
    const float* __restrict__ wk, const float* __restrict__ bk,
    const float* __restrict__ wv, const float* __restrict__ bv,
    const float* __restrict__ w1, const float* __restrict__ b1,
    const float* __restrict__ gamma, const float* __restrict__ beta,
    const float* __restrict__ mean, const float* __restrict__ var,
    float* __restrict__ ws) {
    __shared__ __align__(16) float SMD[STF];
    const int tid  = threadIdx.x;
    const int wave = tid >> 6;
    const int wsub = wave & 3;          // k-slice wave within group
    const int g    = wave >> 2;         // chunk-parity group 0/1
    const int l    = tid & 63;
    const int b    = blockIdx.x;
    const int row16 = l & 15;
    const int quad  = l >> 4;
    const float* xb = x + (size_t)b * XB;

    // ---------------- Gram phase: 2 chunks in flight, 8 iterations ----------
    int offc[3];
#pragma unroll
    for (int r = 0; r < 3; ++r) {
        int c = r * 16 + row16;
        if (c > 33) c = 33;
        offc[r] = (c >= 17) ? (2159 + c) : c;   // = co*2176 + v
    }
    const int koff = wsub * 32 + quad * 8;      // t offset within 128-t chunk

    v4f accG[3][3];
    v4f accS[3];
    {
        v4f vz = {0.f, 0.f, 0.f, 0.f};
#pragma unroll
        for (int r = 0; r < 3; ++r) {
            accS[r] = vz;
#pragma unroll
            for (int c = 0; c < 3; ++c) accG[r][c] = vz;
        }
    }
    v8s ones;
#pragma unroll
    for (int i = 0; i < 8; ++i) ones[i] = (short)0x3F80;   // bf16 1.0

    float* buf0 = SMD + (g * 2 + 0) * 4352;
    float* buf1 = SMD + (g * 2 + 1) * 4352;

    stage_chunk(xb, g * 128, buf0, wsub, l);   // chunk g
    __syncthreads();

    for (int i = 0; i < 8; ++i) {
        const int myChunk = 2 * i + g;
        float* cur = (i & 1) ? buf1 : buf0;
        float* nxt = (i & 1) ? buf0 : buf1;
        if (i < 7) stage_chunk(xb, (myChunk + 2) * 128, nxt, wsub, l);

        const float* rb = cur + koff * 17;
        v8s fh[3], fl4[3];
#pragma unroll
        for (int r = 0; r < 3; ++r) {
            const float* p = rb + offc[r];
            float f[8];
#pragma unroll
            for (int e = 0; e < 8; ++e) f[e] = p[e * 17];
            split8(f, &fh[r], &fl4[r]);
        }
#pragma unroll
        for (int r = 0; r < 3; ++r) {
#pragma unroll
            for (int c = 0; c < 3; ++c) {
                accG[r][c] = __builtin_amdgcn_mfma_f32_16x16x32_bf16(fh[r],  fh[c],  accG[r][c], 0, 0, 0);
                accG[r][c] = __builtin_amdgcn_mfma_f32_16x16x32_bf16(fh[r],  fl4[c], accG[r][c], 0, 0, 0);
                accG[r][c] = __builtin_amdgcn_mfma_f32_16x16x32_bf16(fl4[r], fh[c],  accG[r][c], 0, 0, 0);
            }
            accS[r] = __builtin_amdgcn_mfma_f32_16x16x32_bf16(fh[r],  ones, accS[r], 0, 0, 0);
            accS[r] = __builtin_amdgcn_mfma_f32_16x16x32_bf16(fl4[r], ones, accS[r], 0, 0, 0);
        }
        __syncthreads();   // group buffers safe; both groups in lockstep
    }

    // write 8 wave partials into regions 0..7 ([34][.] + s0 in row 34)
    {
        float* gp = SMD + wave * RSZ;
#pragma unroll
        for (int r = 0; r < 3; ++r) {
#pragma unroll
            for (int c = 0; c < 3; ++c) {
#pragma unroll
                for (int i = 0; i < 4; ++i) {
                    int m = r * 16 + quad * 4 + i;
                    int n = c * 16 + row16;
                    if (m < 34 && n < 34) gp[m * RST + n] = accG[r][c][i];
                }
            }
            if (row16 == 0) {
#pragma unroll
                for (int i = 0; i < 4; ++i) {
                    int m = r * 16 + quad * 4 + i;
                    if (m < 34) gp[34 * RST + m] = accS[r][i];
                }
            }
        }
    }
    __syncthreads();
    // reduce 8 partials into registers (<=3 entries/thread + s0 for tid<34)
    float gred[3];
    int   gm[3], gn[3];
#pragma unroll
    for (int k = 0; k < 3; ++k) {
        int idx = tid + k * 512;
        if (idx < 1156) {
            int m = idx / 34, n = idx - m * 34;
            gm[k] = m; gn[k] = n;
            float s = 0.f;
#pragma unroll
            for (int r = 0; r < 8; ++r) s += SMD[r * RSZ + m * RST + n];
            gred[k] = s;
        } else { gm[k] = -1; gn[k] = 0; gred[k] = 0.f; }
    }
    float s0red = 0.f;
    if (tid < 34) {
#pragma unroll
        for (int r = 0; r < 8; ++r) s0red += SMD[r * RSZ + 34 * RST + tid];
    }
    __syncthreads();
    // zero chain area (pads must be 0 and stay 0)
    {
        const float4 z = make_float4(0.f, 0.f, 0.f, 0.f);
        for (int i = tid * 4; i < SMF; i += 2048) *(float4*)(SMD + i) = z;
    }
    __syncthreads();
    // build augmented G0 + layer-0 shortcut (A=I, a=0)
#pragma unroll
    for (int k = 0; k < 3; ++k)
        if (gm[k] >= 0) SMD[R_G0 + gm[k] * RST + gn[k]] = gred[k];
    for (int idx = tid; idx < 1156; idx += 512) {
        int m = idx / 34, n = idx - m * 34;
        SMD[R_Aq + m * RST + n] = wq[idx];
        SMD[R_Ak + m * RST + n] = wk[idx];
        SMD[R_Av + n * RST + m] = wv[idx];
    }
    if (tid < 34) {
        SMD[R_G0 + 34 * RST + tid] = s0red;
        SMD[R_G0 + tid * RST + 34] = s0red;
        SMD[R_Aq + tid * RST + 34] = bq[tid];
        SMD[R_Ak + tid * RST + 34] = bk[tid];
        SMD[R_Av + 34 * RST + tid] = bv[tid];
    }
    if (tid == 0) SMD[R_G0 + 34 * RST + 34] = 2048.0f;
    __syncthreads();

    // ---------------- Chain phase (tiles split across 8 waves) --------------
    for (int lyr = 0; lyr < 3; ++lyr) {
        if (lyr > 0) {
            const float* wql = wq + lyr * 1156;
            const float* wkl = wk + lyr * 1156;
            const float* wvl = wv + lyr * 1156;
            for (int idx = tid; idx < 1156; idx += 512) {
                int m = idx / 34, n = idx - m * 34;
                SMD[R_S1 + m * RST + n] = wql[idx];
                SMD[R_Sc + m * RST + n] = wkl[idx];
                SMD[R_Wx + m * RST + n] = wvl[idx];
            }
            __syncthreads();
            // stage1: Aq = Wq*A^, Ak = Wk*A^, AvT = (Wv*A^)^T (27 tile tasks)
            for (int t = wave; t < 27; t += 8) {
                int mmI = t / 9, tile = t - mmI * 9;
                int tm = tile / 3, tn = tile - tm * 3;
                int Lo = (mmI == 0) ? R_S1 : (mmI == 1) ? R_Sc : R_Wx;
                int Do = (mmI == 0) ? R_Aq : (mmI == 1) ? R_Ak : R_Av;
                tile_mm(SMD, Lo, R_At, Do, tm, tn, l, mmI == 2);
            }
            __syncthreads();
            if (tid < 34) {     // biases into the offset slots
                SMD[R_Aq + tid * RST + 34] += bq[lyr * 34 + tid];
                SMD[R_Ak + tid * RST + 34] += bk[lyr * 34 + tid];
                SMD[R_Av + 34 * RST + tid] += bv[lyr * 34 + tid];
            }
            __syncthreads();
        }
        // stage2: S1 = Aq^ * G0^  (augmented, symmetric G0)
        for (int t = wave; t < 9; t += 8) {
            int tm = t / 3, tn = t - tm * 3;
            tile_mm(SMD, R_Aq, R_G0, R_S1, tm, tn, l, false);
        }
        __syncthreads();
        // stage3: Sc = S1 * Ak^T (exact augmented scores)
        for (int t = wave; t < 9; t += 8) {
            int tm = t / 3, tn = t - tm * 3;
            tile_mm(SMD, R_S1, R_Ak, R_Sc, tm, tn, l, false);
        }
        __syncthreads();
        // stage4: row softmax (tid<34); tid 64..81 zero Sc rows 34/35
        if (tid < 34) {
            float f[36];
#pragma unroll
            for (int e0 = 0; e0 < 36; e0 += 4)
                *(float4*)&f[e0] = *(const float4*)&SMD[R_Sc + tid * RST + e0];
            const float scale = 0.022097086912079608f;   // 1/sqrt(2048)
            float mx = -1e30f;
#pragma unroll
            for (int d = 0; d < 34; ++d) { f[d] *= scale; mx = fmaxf(mx, f[d]); }
            float sum = 0.f;
#pragma unroll
            for (int d = 0; d < 34; ++d) { float e = __expf(f[d] - mx); f[d] = e; sum += e; }
            float rs = 1.0f / sum;
#pragma unroll
            for (int d = 0; d < 34; ++d) f[d] *= rs;
            f[34] = 0.f; f[35] = 0.f;
#pragma unroll
            for (int e0 = 0; e0 < 36; e0 += 4)
                *(float4*)&SMD[R_Sc + tid * RST + e0] = *(const float4*)&f[e0];
        } else if (tid >= 64 && tid < 82) {
            int u = tid - 64;                     // zero Sc rows 34,35 cols 0..35
            int row = 34 + u / 9, c4 = (u - (u / 9) * 9) * 4;
            *(float4*)&SMD[R_Sc + row * RST + c4] = make_float4(0.f, 0.f, 0.f, 0.f);
        }
        __syncthreads();
        // stage5: At' = AvT^ * attn^T; row 34 propagates the offset
        for (int t = wave; t < 9; t += 8) {
            int tm = t / 3, tn = t - tm * 3;
            tile_mm(SMD, R_Av, R_Sc, R_At, tm, tn, l, false);
        }
        __syncthreads();
    }

    // head: stage w1 (rows 0..15) into Sc, mm -> S1; col34 = W1*a
    for (int idx = tid; idx < 544; idx += 512) {
        int m = idx / 34, n = idx - m * 34;
        SMD[R_Sc + m * RST + n] = w1[idx];
    }
    __syncthreads();
    for (int t = wave; t < 9; t += 8) {
        int tm = t / 3, tn = t - tm * 3;
        tile_mm(SMD, R_Sc, R_At, R_S1, tm, tn, l, false);
    }
    __syncthreads();
    // emit compact Wy': bf16 hi/lo planes (c<32), f32 cols 32/33, cy
    float* wb = ws + (size_t)b * RB_STRIDE;
    if (tid < 16) {
        float iv = gamma[tid] * rsqrtf(var[tid] + 1e-5f);
        float cyraw = SMD[R_S1 + tid * RST + 34] + b1[tid];
        wb[512 + tid] = (cyraw - mean[tid]) * iv + beta[tid];   // cy'
        wb[528 + tid] = SMD[R_S1 + tid * RST + 32] * iv;        // wy32
        wb[544 + tid] = SMD[R_S1 + tid * RST + 33] * iv;        // wy33
    }
    unsigned short* wp = (unsigned short*)wb;
    for (int i = tid; i < 512; i += 512) {
        int o = i >> 5, c = i & 31;
        float iv = gamma[o] * rsqrtf(var[o] + 1e-5f);
        float vv = SMD[R_S1 + o * RST + c] * iv;
        unsigned short hb = f2bf(vv);
        wp[i] = hb;
        wp[512 + i] = f2bf(vv - bf2f(hb));
    }
}

// ---------------------------------------------------------------------------
// K3: out = w2 * leaky(Wy' h0 + cy') + b2.
// ---------------------------------------------------------------------------
__global__ __launch_bounds__(256, 4) void k_out(const float* __restrict__ x,
                                                const float* __restrict__ w2,
                                                const float* __restrict__ b2,
                                                const float* __restrict__ ws,
                                                float* __restrict__ out) {
    __shared__ __align__(16) float raw[2][4352];

    const int tid  = threadIdx.x;
    const int b    = blockIdx.x >> 3;
    const int seg  = (blockIdx.x & 7) * 256;
    const int l    = tid & 63;
    const int w    = tid >> 6;
    const int quad = l >> 4;
    const int col  = l & 15;

    const float* wb = ws + (size_t)b * RB_STRIDE;
    const unsigned short* wp = (const unsigned short*)wb;
    v8s aH = *(const v8s*)&wp[col * 32 + quad * 8];
    v8s aL = *(const v8s*)&wp[512 + col * 32 + quad * 8];
    float cyr[4], w2r[3][4], wy32r[4], wy33r[4];
#pragma unroll
    for (int i = 0; i < 4; ++i) {
        int o = quad * 4 + i;
        cyr[i]   = wb[512 + o];
        wy32r[i] = wb[528 + o];
        wy33r[i] = wb[544 + o];
#pragma unroll
        for (int p = 0; p < 3; ++p) w2r[p][i] = w2[p * 16 + o];
    }
    float b2r[3] = {b2[0], b2[1], b2[2]};
    const float* xb = x + (size_t)b * XB;

    int offq[8];
#pragma unroll
    for (int e = 0; e < 8; ++e) {
        int c = quad * 8 + e;
        offq[e] = (c >= 17) ? (2159 + c) : c;   // = co*2176 + v
    }

    stage_chunk(xb, seg, raw[0], w, l);
    __syncthreads();

    for (int ch = 0; ch < 2; ++ch) {
        if (ch == 0) stage_chunk(xb, seg + 128, raw[1], w, l);
        for (int tt = w; tt < 8; tt += 4) {
            const int tl = tt * 16 + col;
            const float* rbt = raw[ch] + tl * 17;
            float f[8];
#pragma unroll
            for (int e = 0; e < 8; ++e) f[e] = rbt[offq[e]];
            v8s bH, bL;
            split8(f, &bH, &bL);
            v4f acc = {0.f, 0.f, 0.f, 0.f};
            acc = __builtin_amdgcn_mfma_f32_16x16x32_bf16(aH, bH, acc, 0, 0, 0);
            acc = __builtin_amdgcn_mfma_f32_16x16x32_bf16(aH, bL, acc, 0, 0, 0);
            acc = __builtin_amdgcn_mfma_f32_16x16x32_bf16(aL, bH, acc, 0, 0, 0);
            float h32 = rbt[2191];   // c=32 (co1, v15)
            float h33 = rbt[2192];   // c=33 (co1, v16)
            float op[3] = {0, 0, 0};
#pragma unroll
            for (int i = 0; i < 4; ++i) {
                float y = acc[i] + cyr[i] + wy32r[i] * h32 + wy33r[i] * h33;
                float z = (y > 0.f) ? y : 0.01f * y;
#pragma unroll
                for (int p = 0; p < 3; ++p) op[p] += w2r[p][i] * z;
            }
#pragma unroll
            for (int p = 0; p < 3; ++p) {
                op[p] += __shfl_xor(op[p], 16);
                op[p] += __shfl_xor(op[p], 32);
            }
            if (l < 16) {
                int tg = seg + ch * 128 + tt * 16 + l;
#pragma unroll
                for (int p = 0; p < 3; ++p)
                    out[((size_t)b * 3 + p) * 2048 + tg] = op[p] + b2r[p];
            }
        }
        __syncthreads();   // drains chunk-1 stage; protects buffer before exit
    }
}

extern "C" void kernel_launch(void* const* d_in, const int* in_sizes, int n_in,
                              void* d_out, int out_size, void* d_ws, size_t ws_size,
                              hipStream_t stream) {
    const float* x     = (const float*)d_in[0];
    const float* wq    = (const float*)d_in[1];
    const float* bq    = (const float*)d_in[2];
    const float* wk    = (const float*)d_in[3];
    const float* bk    = (const float*)d_in[4];
    const float* wv    = (const float*)d_in[5];
    const float* bv    = (const float*)d_in[6];
    const float* w1    = (const float*)d_in[7];
    const float* b1    = (const float*)d_in[8];
    const float* gamma = (const float*)d_in[9];
    const float* beta  = (const float*)d_in[10];
    const float* mean  = (const float*)d_in[11];
    const float* var   = (const float*)d_in[12];
    const float* w2    = (const float*)d_in[13];
    const float* b2    = (const float*)d_in[14];
    float* ws  = (float*)d_ws;
    float* out = (float*)d_out;

    k_fused<<<dim3(512), dim3(512), 0, stream>>>(x, wq, bq, wk, bk, wv, bv,
                                                 w1, b1, gamma, beta, mean, var, ws);
    k_out<<<dim3(4096), dim3(256), 0, stream>>>(x, w2, b2, ws, out);
}